// Round 1
// baseline (227.784 us; speedup 1.0000x reference)
//
#include <hip/hip_runtime.h>
#include <stdint.h>
#include <math.h>

// HashingDiscretizer — R6: branchless phase-separated MLP restructure.
//
// R5 baseline (62us/dispatch) showed VGPR=36, VALUBusy 21%, HBM 24%:
// the per-element if/else forced the compiler into a fully serialized
// minimal-register schedule (one element's LDS header + 4 gathers at a
// time -> ~1000 cy of exposed L2 latency per element). This version
// removes all hot-path branches and splits the chunk into wide phases:
//   P1: 8x ds_read_b128 spiv headers (all issued back-to-back)
//   P2: classify + quadrant + gather byte-offset (dummy offset 0 for
//       uncalibrated lanes -> wave-uniform line, coalesces in TA)
//   P3: 16x global_load_dwordx4 (stage 1: first 32B of quadrant line)
//   P4: partial strict-less counts (8 of 16 bins)
//   P5: 16x global_load_dwordx4 (stage 2: last 32B, reusing registers)
//   P6: finish counts + hash + branchless select
//   cold: rare mask (key>=16384 or calibrated high key; absent in bench
//         data) -> generic fallback loop.
// 16 loads in flight per wave instead of ~2-4; target ~2x latency win.
//
// ws layout:
//   qtab  [8192][64] f32 (2 MB): row k = 63 boundaries + inf pad; the
//          quadrant q (16 floats at +16q) is ONE 64B line.
//   spiv  [8192] uint4 (128 KB): {f32 b15, f32 b31, f32 b47, u32 k^MAGIC}
//   scal  [8192] bytes  (8 KB): for keys 8192..16383: 0x40|(k&63)
// Poison 0xAA can match neither sentinel, so unwritten rows read as
// uncalibrated — no clear pass needed.

#define GOLDEN   0x9E3779B9u
#define OUT_MASK ((1u << 22) - 1u)
#define NBIN  63
#define NPIV  8192
#define NKEY  16384
#define MAGIC 0xC0FFEE42u

typedef float fx4 __attribute__((ext_vector_type(4)));
typedef int   ix4 __attribute__((ext_vector_type(4)));
typedef unsigned ux4 __attribute__((ext_vector_type(4)));

// ---------------- build (no atomics, no clear) ----------------
__global__ __launch_bounds__(256) void build_tables_kernel(
    const int* __restrict__ fids, const float* __restrict__ bins,
    float* __restrict__ qtab, ux4* __restrict__ spiv_g,
    unsigned char* __restrict__ scal_g, int F)
{
    const int t = blockIdx.x * blockDim.x + threadIdx.x;
    if (t >= F * 64) return;
    const int r = t >> 6;
    const int j = t & 63;
    const int k = fids[r];
    const unsigned uk = (unsigned)k;
    const float* src = bins + (size_t)r * NBIN;

    if (uk < (unsigned)NPIV) {
        qtab[((size_t)uk << 6) + j] = (j < NBIN) ? src[j] : INFINITY;
        if (j == 0) {
            ux4 p;
            p.x = __float_as_uint(src[15]);
            p.y = __float_as_uint(src[31]);
            p.z = __float_as_uint(src[47]);
            p.w = uk ^ MAGIC;
            spiv_g[uk] = p;
        }
    } else if (uk < (unsigned)NKEY && j == 0) {
        scal_g[uk - NPIV] = (unsigned char)(0x40u | (uk & 63u));
    }
}

// ---------------- generic fallback ----------------
__device__ __forceinline__ void hd_fallback(
    int k, float v, const int* __restrict__ fids, const float* __restrict__ bins,
    int F, int fsteps, float& okey, float& oval)
{
    int lo = 0, hi = F;
    for (int s = 0; s < fsteps; ++s) {
        int  mid  = (lo + hi) >> 1;
        int  mids = min(mid, F - 1);
        int  fv   = fids[mids];
        bool valid = lo < hi;
        bool right = valid && (fv < k);
        lo = right ? mid + 1 : lo;
        hi = (valid && !right) ? mid : hi;
    }
    const int  idx_safe   = min(lo, F - 1);
    const bool calibrated = (fids[idx_safe] == k);
    const float* brow = bins + (size_t)idx_safe * NBIN;
    int blo = 0, bhi = NBIN;
    #pragma unroll
    for (int s = 0; s < 6; ++s) {
        int   mid  = (blo + bhi) >> 1;
        int   mids = min(mid, NBIN - 1);
        float bv   = brow[mids];
        bool  valid = blo < bhi;
        bool  right = valid && (bv < v);
        blo = right ? mid + 1 : blo;
        bhi = (valid && !right) ? mid : bhi;
    }
    const uint32_t h = ((uint32_t)k * GOLDEN + (uint32_t)blo) * GOLDEN;
    okey = calibrated ? (float)(h & OUT_MASK) : (float)((uint32_t)k & OUT_MASK);
    oval = calibrated ? 1.0f : v;
}

// ---------------- main ----------------
__global__ __launch_bounds__(1024) void hd_main_kernel(
    const int* __restrict__ keys, const float* __restrict__ vals,
    const int* __restrict__ fids, const float* __restrict__ bins,
    const float* __restrict__ qtab, const ux4* __restrict__ spiv_g,
    const unsigned char* __restrict__ scal_g,
    float* __restrict__ out_keys, float* __restrict__ out_vals,
    int n, int F, int fsteps, int nchunks)
{
    extern __shared__ char smem[];
    ux4*      spiv = reinterpret_cast<ux4*>(smem);               // NPIV x 16B
    unsigned* scal = reinterpret_cast<unsigned*>(smem + (size_t)NPIV * 16);

    const int tid = threadIdx.x;
    for (int i = tid; i < NPIV; i += (int)blockDim.x) spiv[i] = spiv_g[i];
    const unsigned* scal_g32 = reinterpret_cast<const unsigned*>(scal_g);
    for (int i = tid; i < NPIV / 4; i += (int)blockDim.x) scal[i] = scal_g32[i];
    __syncthreads();

    const unsigned char* scal_b = reinterpret_cast<const unsigned char*>(scal);
    const char* qb = reinterpret_cast<const char*>(qtab);
    const int nthreads = (int)(gridDim.x * blockDim.x);

    for (int c = blockIdx.x * blockDim.x + tid; c < nchunks; c += nthreads) {
        const int i0 = c * 8;
        int   ks[8];
        float vs[8];
        const bool full = (i0 + 7 < n);
        if (full) {
            const ix4 ka = __builtin_nontemporal_load(reinterpret_cast<const ix4*>(keys + i0));
            const ix4 kb = __builtin_nontemporal_load(reinterpret_cast<const ix4*>(keys + i0 + 4));
            const fx4 va = __builtin_nontemporal_load(reinterpret_cast<const fx4*>(vals + i0));
            const fx4 vb = __builtin_nontemporal_load(reinterpret_cast<const fx4*>(vals + i0 + 4));
            ks[0]=ka.x; ks[1]=ka.y; ks[2]=ka.z; ks[3]=ka.w;
            ks[4]=kb.x; ks[5]=kb.y; ks[6]=kb.z; ks[7]=kb.w;
            vs[0]=va.x; vs[1]=va.y; vs[2]=va.z; vs[3]=va.w;
            vs[4]=vb.x; vs[5]=vb.y; vs[6]=vb.z; vs[7]=vb.w;
        } else {
            #pragma unroll
            for (int j = 0; j < 8; ++j) {
                int idx = min(i0 + j, n - 1);
                ks[j] = keys[idx];
                vs[j] = vals[idx];
            }
        }

        // ---- P1: all 8 spiv headers (independent ds_read_b128) ----
        ux4 hdr[8];
        #pragma unroll
        for (int j = 0; j < 8; ++j) {
            const unsigned uk = (unsigned)ks[j];
            hdr[j] = spiv[uk < (unsigned)NPIV ? uk : 0u];
        }

        // ---- P2: classify, quadrant, byte offsets, rare mask ----
        unsigned off[8];
        int      qcnt[8];
        unsigned calm = 0u, rare = 0u;
        #pragma unroll
        for (int j = 0; j < 8; ++j) {
            const unsigned uk = (unsigned)ks[j];
            const float v = vs[j];
            const bool low = uk < (unsigned)NPIV;
            const bool cal = low && (hdr[j].w == (uk ^ MAGIC));
            const int q = (__uint_as_float(hdr[j].x) < v)
                        + (__uint_as_float(hdr[j].y) < v)
                        + (__uint_as_float(hdr[j].z) < v);
            off[j]  = cal ? ((uk << 8) + (unsigned)(q << 6)) : 0u;
            qcnt[j] = q << 4;
            calm   |= cal ? (1u << j) : 0u;
            // high-key calibrated check (LDS byte, branchless)
            const unsigned hs = uk - (unsigned)NPIV;
            const bool hi = hs < (unsigned)NPIV;            // NPIV<=uk<NKEY
            const bool calhi = hi && (scal_b[hi ? hs : 0u]
                              == (unsigned char)(0x40u | (uk & 63u)));
            rare |= (calhi || (uk >= (unsigned)NKEY)) ? (1u << j) : 0u;
        }

        // ---- P3: stage-1 gathers (first 32B of quadrant line) ----
        fx4 gA[8], gB[8];
        #pragma unroll
        for (int j = 0; j < 8; ++j) {
            const char* p = qb + off[j];
            gA[j] = *reinterpret_cast<const fx4*>(p);
            gB[j] = *reinterpret_cast<const fx4*>(p + 16);
        }
        // ---- P4: partial counts ----
        #pragma unroll
        for (int j = 0; j < 8; ++j) {
            const float v = vs[j];
            qcnt[j] += (gA[j].x<v)+(gA[j].y<v)+(gA[j].z<v)+(gA[j].w<v)
                     + (gB[j].x<v)+(gB[j].y<v)+(gB[j].z<v)+(gB[j].w<v);
        }
        // ---- P5: stage-2 gathers (last 32B, registers reused) ----
        #pragma unroll
        for (int j = 0; j < 8; ++j) {
            const char* p = qb + off[j];
            gA[j] = *reinterpret_cast<const fx4*>(p + 32);
            gB[j] = *reinterpret_cast<const fx4*>(p + 48);
        }
        // ---- P6: finish counts + hash + branchless select ----
        float ok[8], ov[8];
        #pragma unroll
        for (int j = 0; j < 8; ++j) {
            const unsigned uk = (unsigned)ks[j];
            const float v = vs[j];
            const int cnt = qcnt[j]
                + (gA[j].x<v)+(gA[j].y<v)+(gA[j].z<v)+(gA[j].w<v)
                + (gB[j].x<v)+(gB[j].y<v)+(gB[j].z<v)+(gB[j].w<v);
            const uint32_t h = (uk * GOLDEN + (uint32_t)cnt) * GOLDEN;
            const bool cal = (calm >> j) & 1u;
            ok[j] = cal ? (float)(h & OUT_MASK) : (float)(uk & OUT_MASK);
            ov[j] = cal ? 1.0f : v;
        }

        // ---- cold path: key>=NKEY or calibrated high key (never in bench)
        if (__builtin_expect(rare != 0u, 0)) {
            #pragma unroll 1
            for (int j = 0; j < 8; ++j)
                if ((rare >> j) & 1u)
                    hd_fallback(ks[j], vs[j], fids, bins, F, fsteps, ok[j], ov[j]);
        }

        if (full) {
            fx4 a, b;
            a.x=ok[0]; a.y=ok[1]; a.z=ok[2]; a.w=ok[3];
            b.x=ok[4]; b.y=ok[5]; b.z=ok[6]; b.w=ok[7];
            __builtin_nontemporal_store(a, reinterpret_cast<fx4*>(out_keys + i0));
            __builtin_nontemporal_store(b, reinterpret_cast<fx4*>(out_keys + i0 + 4));
            a.x=ov[0]; a.y=ov[1]; a.z=ov[2]; a.w=ov[3];
            b.x=ov[4]; b.y=ov[5]; b.z=ov[6]; b.w=ov[7];
            __builtin_nontemporal_store(a, reinterpret_cast<fx4*>(out_vals + i0));
            __builtin_nontemporal_store(b, reinterpret_cast<fx4*>(out_vals + i0 + 4));
        } else {
            for (int j = 0; j < 8 && i0 + j < n; ++j) {
                out_keys[i0 + j] = ok[j];
                out_vals[i0 + j] = ov[j];
            }
        }
    }
}

// Pure binary-search kernel: used only if LDS or workspace is insufficient.
__global__ __launch_bounds__(256) void hd_simple_kernel(
    const int* __restrict__ keys, const float* __restrict__ vals,
    const int* __restrict__ fids, const float* __restrict__ bins,
    float* __restrict__ out_keys, float* __restrict__ out_vals,
    int n, int F, int fsteps)
{
    const int gid = blockIdx.x * blockDim.x + threadIdx.x;
    const int i0 = gid * 4;
    if (i0 >= n) return;
    #pragma unroll
    for (int j = 0; j < 4; ++j) {
        int idx = min(i0 + j, n - 1);
        float okey, oval;
        hd_fallback(keys[idx], vals[idx], fids, bins, F, fsteps, okey, oval);
        if (i0 + j < n) { out_keys[i0 + j] = okey; out_vals[i0 + j] = oval; }
    }
}

extern "C" void kernel_launch(void* const* d_in, const int* in_sizes, int n_in,
                              void* d_out, int out_size, void* d_ws, size_t ws_size,
                              hipStream_t stream) {
    const int*   keys = (const int*)d_in[0];
    const float* vals = (const float*)d_in[1];
    const int*   fids = (const int*)d_in[2];
    const float* bins = (const float*)d_in[3];

    const int n = in_sizes[0];
    const int F = in_sizes[2];

    int fsteps = 0;
    while ((1 << fsteps) < F + 1) ++fsteps;

    float* out_keys = (float*)d_out;
    float* out_vals = (float*)d_out + n;

    // ws: qtab (2 MB) | spiv (128 KB) | scal (8 KB)
    const size_t qtab_bytes = (size_t)NPIV * 64 * sizeof(float);
    const size_t spiv_bytes = (size_t)NPIV * 16;
    const size_t scal_bytes = (size_t)NPIV;
    const size_t ws_need    = qtab_bytes + spiv_bytes + scal_bytes;
    const size_t lds_bytes  = spiv_bytes + scal_bytes;   // 139264 B

    int max_lds = 0;
    hipDeviceGetAttribute(&max_lds, hipDeviceAttributeMaxSharedMemoryPerBlock, 0);

    const bool fast = (ws_size >= ws_need) && ((size_t)max_lds >= lds_bytes) &&
                      (in_sizes[3] == F * NBIN);

    if (fast) {
        float*         qtab   = (float*)d_ws;
        ux4*           spiv_g = (ux4*)((char*)d_ws + qtab_bytes);
        unsigned char* scal_g = (unsigned char*)d_ws + qtab_bytes + spiv_bytes;

        build_tables_kernel<<<(F * 64 + 255) / 256, 256, 0, stream>>>(
            fids, bins, qtab, spiv_g, scal_g, F);

        (void)hipFuncSetAttribute(
            reinterpret_cast<const void*>(hd_main_kernel),
            hipFuncAttributeMaxDynamicSharedMemorySize, (int)lds_bytes);

        const int threads = 1024;
        const int nblocks = 256;           // 1 block/CU; LDS fill once per CU
        const int nchunks = (n + 7) / 8;
        hd_main_kernel<<<nblocks, threads, lds_bytes, stream>>>(
            keys, vals, fids, bins, qtab, spiv_g, scal_g,
            out_keys, out_vals, n, F, fsteps, nchunks);
    } else {
        const int threads = 256;
        const int grid = (n + threads * 4 - 1) / (threads * 4);
        hd_simple_kernel<<<grid, threads, 0, stream>>>(
            keys, vals, fids, bins, out_keys, out_vals, n, F, fsteps);
    }
}